// Round 10
// baseline (4124.962 us; speedup 1.0000x reference)
//
#include <hip/hip_runtime.h>

#define NN 50000
#define NE 1600000
#define EP (NE + NN)          // edges + self loops = 1,650,000
#define D 128
#define H 4
#define NEG 0.2f
#define LN_EPS 1e-5f
#define NBUCK 49              // dst >> 10 buckets
#define BCAP 40960            // fixed bucket capacity (max ~35.5K used)
#define CHUNK 4096
#define CSH 13                // src chunk shift: chunk = src >> 13, 0..6
#define NGRP 6250             // 8-node groups
#define NSEG (NGRP * 8)       // (group, chunk) segments, 8 chunk slots (7 used)

typedef _Float16 f16;
typedef _Float16 half8 __attribute__((ext_vector_type(8)));
typedef _Float16 half2v __attribute__((ext_vector_type(2)));
typedef float f32x4v __attribute__((ext_vector_type(4)));
typedef unsigned short u16;
typedef unsigned int u32;

static __device__ __forceinline__ float leakyf(float v) { return fmaxf(v, NEG * v); }

static __device__ __forceinline__ int fkey(float v) {
    int b = __float_as_int(v);
    return b >= 0 ? b : (b ^ 0x7fffffff);
}
static __device__ __forceinline__ float fdec(int k) {
    return __int_as_float(k >= 0 ? k : (k ^ 0x7fffffff));
}
#define NEG_INF_KEY 0x807fffff

// ---------- init: zero deg/gmax/gcur + W->fp16 transposed + ws = W@B' ----------
__global__ void k_init(int* __restrict__ deg, int* __restrict__ gmaxk,
                       int* __restrict__ gcur,
                       const float* __restrict__ w0, const float* __restrict__ w1,
                       const float* __restrict__ w2, f16* __restrict__ wt,
                       const float* __restrict__ as0, const float* __restrict__ ad0,
                       const float* __restrict__ as1, const float* __restrict__ ad1,
                       const float* __restrict__ as2, const float* __restrict__ ad2,
                       f16* __restrict__ ws16) {
    int t = blockIdx.x * blockDim.x + threadIdx.x;
    if (t < NSEG) deg[t] = 0;
    if (t < 12) gmaxk[t] = NEG_INF_KEY;
    if (t < NBUCK) gcur[t] = 0;
    int u = t - 50176;
    if (u >= 0 && u < 3 * D * D) {
        int l = u / (D * D), rem = u % (D * D);
        int k = rem >> 7, c = rem & 127;
        const float* w = (l == 0) ? w0 : (l == 1) ? w1 : w2;
        wt[l * D * D + c * D + k] = (f16)w[rem];
    }
    int v = t - 99328;
    if (v >= 0 && v < 3 * 16 * D) {
        int l = v / (16 * D), rem = v % (16 * D);
        int c = rem >> 7, k = rem & 127;
        f16 out = (f16)0.f;
        if (c < 8) {
            int head = c >> 1;
            const float* w = (l == 0) ? w0 : (l == 1) ? w1 : w2;
            const float* av = (c & 1) ? ((l == 0) ? ad0 : (l == 1) ? ad1 : ad2)
                                      : ((l == 0) ? as0 : (l == 1) ? as1 : as2);
            float s = 0.f;
#pragma unroll
            for (int j = 0; j < 32; j++)
                s = fmaf(w[k * D + head * 32 + j], av[head * 32 + j], s);
            out = (f16)s;
        }
        ws16[l * 16 * D + c * D + k] = out;
    }
}

// phase 1: bin edges into fixed-capacity per-bucket streams (packed dst<<16|src)
__global__ __launch_bounds__(256) void k_bin(const int* __restrict__ ei,
                                             int* __restrict__ gcur,
                                             u32* __restrict__ binned) {
    __shared__ u32 pk[CHUNK];
    __shared__ int hist[NBUCK], base[NBUCK], lcur[NBUCK];
    int tid = threadIdx.x;
    int cbase = blockIdx.x * CHUNK;
    if (tid < NBUCK) hist[tid] = 0;
    __syncthreads();
#pragma unroll
    for (int j = 0; j < CHUNK / 256; j++) {
        int k = cbase + j * 256 + tid;
        u32 v = 0xFFFFFFFFu;
        if (k < EP) {
            int src, dst;
            if (k < NE) { src = ei[k]; dst = ei[NE + k]; }
            else        { src = k - NE; dst = src; }
            v = ((u32)dst << 16) | (u32)src;
            atomicAdd(&hist[dst >> 10], 1);
        }
        pk[j * 256 + tid] = v;
    }
    __syncthreads();
    if (tid < NBUCK) {
        base[tid] = atomicAdd(&gcur[tid], hist[tid]);
        lcur[tid] = 0;
    }
    __syncthreads();
#pragma unroll
    for (int j = 0; j < CHUNK / 256; j++) {
        u32 v = pk[j * 256 + tid];
        if (v != 0xFFFFFFFFu) {
            int b = v >> 26;  // (v>>16)>>10
            int pos = base[b] + atomicAdd(&lcur[b], 1);
            binned[(size_t)b * BCAP + pos] = v;
        }
    }
}

// per-(group,chunk) degree count via 4KB LDS histogram (4 blocks per bucket)
__global__ __launch_bounds__(1024) void k_cnt2(const int* __restrict__ gcur,
                                               const u32* __restrict__ binned,
                                               int* __restrict__ deg) {
    __shared__ int hist[1024];   // 128 groups x 8 chunk slots
    int b = blockIdx.x >> 2, sub = blockIdx.x & 3;
    hist[threadIdx.x] = 0;
    __syncthreads();
    int cnt = gcur[b];
    const u32* bb = binned + (size_t)b * BCAP;
    for (int i = sub * 1024 + threadIdx.x; i < cnt; i += 4096) {
        u32 v = bb[i];
        int idx = (int)(((v >> 16) & 1023) >> 3) * 8 + (int)((v & 0xffffu) >> CSH);
        atomicAdd(&hist[idx], 1);
    }
    __syncthreads();
    int seg = (b << 10) + threadIdx.x;
    if (seg < NSEG && hist[threadIdx.x]) atomicAdd(&deg[seg], hist[threadIdx.x]);
}

#define SCAN_B 512
__global__ void k_scan1(const int* __restrict__ deg, int* __restrict__ stmp, int* __restrict__ bsum) {
    __shared__ int sm[SCAN_B];
    int i = blockIdx.x * SCAN_B + threadIdx.x;
    sm[threadIdx.x] = (i < NSEG) ? ((deg[i] + 3) & ~3) : 0;   // 4-aligned segments
    __syncthreads();
    for (int off = 1; off < SCAN_B; off <<= 1) {
        int t = (threadIdx.x >= off) ? sm[threadIdx.x - off] : 0;
        __syncthreads();
        sm[threadIdx.x] += t;
        __syncthreads();
    }
    if (i < NSEG) stmp[i] = sm[threadIdx.x];
    if (threadIdx.x == SCAN_B - 1) bsum[blockIdx.x] = sm[SCAN_B - 1];
}

__global__ void k_scan2(int* __restrict__ bsum, int nb) {
    __shared__ int sm[256];
    int v = (threadIdx.x < nb) ? bsum[threadIdx.x] : 0;
    sm[threadIdx.x] = v;
    __syncthreads();
    for (int off = 1; off < 256; off <<= 1) {
        int t = (threadIdx.x >= off) ? sm[threadIdx.x - off] : 0;
        __syncthreads();
        sm[threadIdx.x] += t;
        __syncthreads();
    }
    if (threadIdx.x < nb) bsum[threadIdx.x] = sm[threadIdx.x];
}

__global__ void k_scan3(const int* __restrict__ stmp, const int* __restrict__ bsum, int* __restrict__ rowptr) {
    int i = blockIdx.x * SCAN_B + threadIdx.x;
    if (i >= NSEG) return;
    int add = (blockIdx.x > 0) ? bsum[blockIdx.x - 1] : 0;
    rowptr[i + 1] = stmp[i] + add;
    if (i == 0) rowptr[0] = 0;
}

// sentinel-pad each segment tail to the 4-aligned boundary; init cur = rowptr
__global__ void k_pad(const int* __restrict__ rowptr, const int* __restrict__ deg,
                      int* __restrict__ cur, u32* __restrict__ csr) {
    int i = blockIdx.x * blockDim.x + threadIdx.x;
    if (i >= NSEG) return;
    int rp = rowptr[i];
    cur[i] = rp;
    int d = deg[i];
    int ad = (d + 3) & ~3;
    for (int j = d; j < ad; ++j) csr[rp + j] = 0xFFFFFFFFu;
}

// phase 2: per-bucket scatter into (group, chunk) segments (4 blocks per bucket)
__global__ __launch_bounds__(1024) void k_scatter(const int* __restrict__ gcur,
                                                  int* __restrict__ cur,
                                                  const u32* __restrict__ binned,
                                                  u32* __restrict__ csr) {
    int b = blockIdx.x >> 2, sub = blockIdx.x & 3;
    int cnt = gcur[b];
    const u32* bb = binned + (size_t)b * BCAP;
    for (int i = sub * 1024 + threadIdx.x; i < cnt; i += 4096) {
        u32 v = bb[i];
        int dst = v >> 16;
        int src = v & 0xffffu;
        int seg = (dst >> 3) * 8 + (src >> CSH);
        int pos = atomicAdd(&cur[seg], 1);
        csr[pos] = ((u32)(dst & 7) << 16) | (u32)src;
    }
}

// ------------------------- input projection (fp16 residual carry) ---------------
__global__ void k_in(const float* __restrict__ x, const float* __restrict__ w,
                     const float* __restrict__ b, f16* __restrict__ h16) {
    int t = blockIdx.x * blockDim.x + threadIdx.x;
    if (t >= NN * D) return;
    int n = t >> 7, d = t & 127;
    const float* xr = x + n * 5;
    float acc = b[d];
#pragma unroll
    for (int k = 0; k < 5; k++) acc = fmaf(xr[k], w[k * D + d], acc);
    h16[t] = (f16)acc;
}

// --- MFMA GEMM: xh = h16 @ W16; als/ald via extra MFMA tile (ws); global max ---
__global__ __launch_bounds__(256) void k_gemm(const f16* __restrict__ h16,
                                              const f16* __restrict__ wt,
                                              const f16* __restrict__ ws16,
                                              f16* __restrict__ xh,
                                              float* __restrict__ als,
                                              float* __restrict__ ald,
                                              int* __restrict__ gmaxk) {
    __shared__ int sgk[4];
    if (threadIdx.x < 4) sgk[threadIdx.x] = NEG_INF_KEY;
    int wid = threadIdx.x >> 6;
    int lane = threadIdx.x & 63;
    int wbase = blockIdx.x * 128 + wid * 32;
    int r = lane & 15;
    int g = lane >> 4;

    int arow0 = wbase + r;      if (arow0 >= NN) arow0 = NN - 1;
    int arow1 = wbase + 16 + r; if (arow1 >= NN) arow1 = NN - 1;
    const f16* a0p = h16 + (size_t)arow0 * D + g * 8;
    const f16* a1p = h16 + (size_t)arow1 * D + g * 8;

    f32x4v acc0[8], acc1[8], al0, al1;
#pragma unroll
    for (int nt = 0; nt < 8; nt++) {
        acc0[nt] = (f32x4v){0.f, 0.f, 0.f, 0.f};
        acc1[nt] = (f32x4v){0.f, 0.f, 0.f, 0.f};
    }
    al0 = (f32x4v){0.f, 0.f, 0.f, 0.f};
    al1 = (f32x4v){0.f, 0.f, 0.f, 0.f};

#pragma unroll
    for (int ks = 0; ks < 4; ks++) {
        half8 a0 = *(const half8*)(a0p + ks * 32);
        half8 a1 = *(const half8*)(a1p + ks * 32);
        half8 bal = *(const half8*)(ws16 + (size_t)r * D + ks * 32 + g * 8);
        al0 = __builtin_amdgcn_mfma_f32_16x16x32_f16(a0, bal, al0, 0, 0, 0);
        al1 = __builtin_amdgcn_mfma_f32_16x16x32_f16(a1, bal, al1, 0, 0, 0);
#pragma unroll
        for (int nt = 0; nt < 8; nt++) {
            half8 b = *(const half8*)(wt + (size_t)(nt * 16 + r) * D + ks * 32 + g * 8);
            acc0[nt] = __builtin_amdgcn_mfma_f32_16x16x32_f16(a0, b, acc0[nt], 0, 0, 0);
            acc1[nt] = __builtin_amdgcn_mfma_f32_16x16x32_f16(a1, b, acc1[nt], 0, 0, 0);
        }
    }

#pragma unroll
    for (int rg = 0; rg < 4; rg++) {
        int n0 = wbase + g * 4 + rg;
        if (n0 < NN) {
#pragma unroll
            for (int nt = 0; nt < 8; nt++)
                xh[(size_t)n0 * D + nt * 16 + r] = (f16)acc0[nt][rg];
        }
        int n1 = wbase + 16 + g * 4 + rg;
        if (n1 < NN) {
#pragma unroll
            for (int nt = 0; nt < 8; nt++)
                xh[(size_t)n1 * D + nt * 16 + r] = (f16)acc1[nt][rg];
        }
    }

    float m = -1e30f;
#pragma unroll
    for (int rg = 0; rg < 4; rg++) {
        int n0 = wbase + g * 4 + rg;
        int n1 = wbase + 16 + g * 4 + rg;
        float v0 = al0[rg], v1 = al1[rg];
        if (r < 8) {
            int hh = r >> 1;
            if (r & 1) {
                if (n0 < NN) ald[n0 * H + hh] = v0;
                if (n1 < NN) ald[n1 * H + hh] = v1;
            } else {
                if (n0 < NN) als[n0 * H + hh] = v0;
                if (n1 < NN) als[n1 * H + hh] = v1;
                m = fmaxf(m, fmaxf(v0, v1));
            }
        }
    }
    m = fmaxf(m, __shfl_xor(m, 16));
    m = fmaxf(m, __shfl_xor(m, 32));
    __syncthreads();
    if (lane < 8 && !(r & 1)) atomicMax(&sgk[r >> 1], fkey(m));
    __syncthreads();
    if (threadIdx.x < 4) atomicMax(&gmaxk[threadIdx.x], sgk[threadIdx.x]);
}

// ---- lockstep chunked aggregation, 8-node groups, LDS accumulators ----
// wave owns 8 nodes; per chunk one contiguous segment of (nidx<<16|src) records.
// lane = slot(2b) | q(4b): slot = edge slot 0..3, q -> dims q*8..q*8+7, head = q>>2
#define APAD 132
__global__ __launch_bounds__(256, 6) void k_agg(const f16* __restrict__ xh,
                                                const float* __restrict__ als,
                                                const float* __restrict__ ald,
                                                const int* __restrict__ gmaxk,
                                                const int* __restrict__ rp,
                                                const u32* __restrict__ csr,
                                                const float* __restrict__ cb,
                                                const float* __restrict__ gamma,
                                                const float* __restrict__ beta,
                                                f16* __restrict__ h16,
                                                float* __restrict__ hout, int do_relu) {
    __shared__ float accS[4][8 * APAD];   // 16.9 KB
    __shared__ float denS[4][32];
    __shared__ float adhS[4][32];
    __shared__ float mhS[4][32];

    int wid = threadIdx.x >> 6;
    int lane = threadIdx.x & 63;
    int group = blockIdx.x * 4 + wid;
    if (group >= NGRP) group = NGRP - 1;   // duplicate work, identical output (no early exit)
    int nbase = group * 8;
    int slot = lane >> 4;
    int q = lane & 15;
    int head = q >> 2;

    float* accW = accS[wid];
    float* denW = denS[wid];
    float* adhW = adhS[wid];
    float* mhW = mhS[wid];

    for (int i = lane; i < 8 * APAD; i += 64) accW[i] = 0.f;
    if (lane < 32) {
        denW[lane] = 0.f;
        int n = lane >> 2, hh = lane & 3;
        float adh = ald[(nbase + n) * H + hh];
        adhW[lane] = adh;
        mhW[lane] = leakyf(fdec(gmaxk[hh]) + adh);
    }
    __syncthreads();

    for (int p = 0; p < 7; ++p) {
        int seg = group * 8 + p;
        int s0 = rp[seg], s1 = rp[seg + 1];
#pragma unroll 2
        for (int e = s0; e < s1; e += 4) {
            u32 cw = csr[e + slot];
            bool valid = cw != 0xFFFFFFFFu;
            int sc = (int)(cw & 0xffffu);
            int ni = (int)((cw >> 16) & 7u);
            if (!valid) sc = 0;
            float al = als[sc * H + head];
            float ev = valid ? __expf(leakyf(al + adhW[ni * 4 + head]) - mhW[ni * 4 + head]) : 0.f;
            if ((q & 3) == 0) atomicAdd(&denW[ni * 4 + head], ev);
            half8 pv = *(const half8*)(xh + (size_t)sc * D + q * 8);
#pragma unroll
            for (int j0 = 0; j0 < 8; j0++) {
                int jj = (j0 + q) & 7;     // rotated order -> spread LDS banks
                atomicAdd(&accW[ni * APAD + q * 8 + jj], ev * (float)pv[jj]);
            }
        }
    }
    __syncthreads();   // per-wave data only, but cheap and safe

    // epilogue: lane covers dims (2*lane, 2*lane+1); head = lane>>4
    int dim = 2 * lane;
    int ehead = lane >> 4;
    float2 cb2 = ((const float2*)cb)[lane];
    float2 g2 = ((const float2*)gamma)[lane];
    float2 b2 = ((const float2*)beta)[lane];
#pragma unroll
    for (int n = 0; n < 8; n++) {
        int node = nbase + n;
        float den = denW[n * 4 + ehead];
        float a0 = accW[n * APAD + dim];
        float a1 = accW[n * APAD + dim + 1];
        float inv_den = 1.f / (den + 1e-16f);
        float o0 = fmaf(a0, inv_den, cb2.x);
        float o1 = fmaf(a1, inv_den, cb2.y);

        float s = o0 + o1;
#pragma unroll
        for (int off = 32; off; off >>= 1) s += __shfl_xor(s, off);
        float mean = s * (1.f / 128.f);
        float c0 = o0 - mean, c1 = o1 - mean;
        float v = c0 * c0 + c1 * c1;
#pragma unroll
        for (int off = 32; off; off >>= 1) v += __shfl_xor(v, off);
        float inv = rsqrtf(v * (1.f / 128.f) + LN_EPS);

        float r0 = c0 * inv * g2.x + b2.x;
        float r1 = c1 * inv * g2.y + b2.y;
        if (do_relu) { r0 = fmaxf(r0, 0.f); r1 = fmaxf(r1, 0.f); }
        half2v hv16 = *(const half2v*)&h16[(size_t)node * D + dim];
        float n0 = (float)hv16[0] + r0;
        float n1 = (float)hv16[1] + r1;
        if (do_relu) {
            half2v h2; h2[0] = (f16)n0; h2[1] = (f16)n1;
            *(half2v*)&h16[(size_t)node * D + dim] = h2;
        } else {
            *(float2*)&hout[(size_t)node * D + dim] = (float2){n0, n1};
        }
    }
}

// ------------------------- launch -------------------------
extern "C" void kernel_launch(void* const* d_in, const int* in_sizes, int n_in,
                              void* d_out, int out_size, void* d_ws, size_t ws_size,
                              hipStream_t stream) {
    const float* x    = (const float*)d_in[0];
    const float* w_in = (const float*)d_in[1];
    const float* b_in = (const float*)d_in[2];
    const int*   ei   = (const int*)d_in[21];
    float* hout = (float*)d_out;

    char* w = (char*)d_ws;
    int* deg    = (int*)w;  w += (size_t)NSEG * 4;
    int* cur    = (int*)w;  w += (size_t)NSEG * 4;
    int* stmp   = (int*)w;  w += (size_t)NSEG * 4;
    int* bsum   = (int*)w;  w += 1024;
    int* rowptr = (int*)w;  w += (size_t)(NSEG + 8) * 4;
    int* gmaxk  = (int*)w;  w += 64;
    int* gcur   = (int*)w;  w += 256;
    u32* csr    = (u32*)w;  w += (size_t)(EP + 3 * NSEG + 64) * 4;
    f16* h16    = (f16*)w;  w += (size_t)NN * D * 2;
    f16* xh     = (f16*)w;  w += (size_t)NN * D * 2;
    f16* wt     = (f16*)w;  w += (size_t)3 * D * D * 2;
    f16* ws16   = (f16*)w;  w += (size_t)3 * 16 * D * 2;
    float* als  = (float*)w; w += (size_t)NN * H * 4;
    float* ald  = (float*)w; w += (size_t)NN * H * 4;
    u32* binned = (u32*)h16;  // h16 first written by k_in AFTER scatter; 8.03MB < 12.8MB

    k_init<<<412, 256, 0, stream>>>(deg, gmaxk, gcur,
                                    (const float*)d_in[3], (const float*)d_in[9],
                                    (const float*)d_in[15], wt,
                                    (const float*)d_in[4], (const float*)d_in[5],
                                    (const float*)d_in[10], (const float*)d_in[11],
                                    (const float*)d_in[16], (const float*)d_in[17],
                                    ws16);
    k_bin<<<(EP + CHUNK - 1) / CHUNK, 256, 0, stream>>>(ei, gcur, binned);
    k_cnt2<<<NBUCK * 4, 1024, 0, stream>>>(gcur, binned, deg);
    int nbScan = (NSEG + SCAN_B - 1) / SCAN_B;  // 98
    k_scan1<<<nbScan, SCAN_B, 0, stream>>>(deg, stmp, bsum);
    k_scan2<<<1, 256, 0, stream>>>(bsum, nbScan);
    k_scan3<<<nbScan, SCAN_B, 0, stream>>>(stmp, bsum, rowptr);
    k_pad<<<(NSEG + 255) / 256, 256, 0, stream>>>(rowptr, deg, cur, csr);
    k_scatter<<<NBUCK * 4, 1024, 0, stream>>>(gcur, cur, binned, csr);

    k_in<<<(NN * D) / 256, 256, 0, stream>>>(x, w_in, b_in, h16);

    int aggBlocks = (NGRP + 3) / 4;   // 1563
    for (int L = 0; L < 3; ++L) {
        const float* cb   = (const float*)d_in[6 + 6 * L];
        const float* g    = (const float*)d_in[7 + 6 * L];
        const float* lb   = (const float*)d_in[8 + 6 * L];
        k_gemm<<<(NN + 127) / 128, 256, 0, stream>>>(h16, wt + (size_t)L * D * D,
                                                     ws16 + (size_t)L * 16 * D,
                                                     xh, als, ald, gmaxk + 4 * L);
        k_agg<<<aggBlocks, 256, 0, stream>>>(xh, als, ald, gmaxk + 4 * L, rowptr, csr,
                                             cb, g, lb, h16, hout, L < 2 ? 1 : 0);
    }
}

// Round 11
// 417.990 us; speedup vs baseline: 9.8686x; 9.8686x over previous
//
#include <hip/hip_runtime.h>

#define NN 50000
#define NE 1600000
#define EP (NE + NN)          // edges + self loops = 1,650,000
#define D 128
#define H 4
#define NEG 0.2f
#define LN_EPS 1e-5f
#define NBUCK 49              // dst >> 10 buckets
#define BCAP 40960            // fixed bucket capacity (max ~35.5K used)
#define CHUNK 4096
#define NCHUNK 4              // src chunks (src >> 14), 4MB xh window each
#define CSH 14
#define NSEG (NN * NCHUNK)    // 200000 (node, chunk) segments

typedef _Float16 f16;
typedef _Float16 half8 __attribute__((ext_vector_type(8)));
typedef _Float16 half2v __attribute__((ext_vector_type(2)));
typedef float f32x4v __attribute__((ext_vector_type(4)));
typedef unsigned short u16;
typedef unsigned int u32;

static __device__ __forceinline__ float leakyf(float v) { return fmaxf(v, NEG * v); }

static __device__ __forceinline__ int fkey(float v) {
    int b = __float_as_int(v);
    return b >= 0 ? b : (b ^ 0x7fffffff);
}
static __device__ __forceinline__ float fdec(int k) {
    return __int_as_float(k >= 0 ? k : (k ^ 0x7fffffff));
}
#define NEG_INF_KEY 0x807fffff

// ---------- init: zero deg/gmax/gcur + W->fp16 transposed + ws = W@B' ----------
__global__ void k_init(int* __restrict__ deg, int* __restrict__ gmaxk,
                       int* __restrict__ gcur,
                       const float* __restrict__ w0, const float* __restrict__ w1,
                       const float* __restrict__ w2, f16* __restrict__ wt,
                       const float* __restrict__ as0, const float* __restrict__ ad0,
                       const float* __restrict__ as1, const float* __restrict__ ad1,
                       const float* __restrict__ as2, const float* __restrict__ ad2,
                       f16* __restrict__ ws16) {
    int t = blockIdx.x * blockDim.x + threadIdx.x;
    if (t < NSEG) deg[t] = 0;
    if (t < 12) gmaxk[t] = NEG_INF_KEY;
    if (t < NBUCK) gcur[t] = 0;
    int u = t - 50176;
    if (u >= 0 && u < 3 * D * D) {
        int l = u / (D * D), rem = u % (D * D);
        int k = rem >> 7, c = rem & 127;
        const float* w = (l == 0) ? w0 : (l == 1) ? w1 : w2;
        wt[l * D * D + c * D + k] = (f16)w[rem];
    }
    int v = t - 99328;
    if (v >= 0 && v < 3 * 16 * D) {
        int l = v / (16 * D), rem = v % (16 * D);
        int c = rem >> 7, k = rem & 127;
        f16 out = (f16)0.f;
        if (c < 8) {
            int head = c >> 1;
            const float* w = (l == 0) ? w0 : (l == 1) ? w1 : w2;
            const float* av = (c & 1) ? ((l == 0) ? ad0 : (l == 1) ? ad1 : ad2)
                                      : ((l == 0) ? as0 : (l == 1) ? as1 : as2);
            float s = 0.f;
#pragma unroll
            for (int j = 0; j < 32; j++)
                s = fmaf(w[k * D + head * 32 + j], av[head * 32 + j], s);
            out = (f16)s;
        }
        ws16[l * 16 * D + c * D + k] = out;
    }
}

// phase 1: bin edges into fixed-capacity per-bucket streams (packed dst<<16|src)
__global__ __launch_bounds__(256) void k_bin(const int* __restrict__ ei,
                                             int* __restrict__ gcur,
                                             u32* __restrict__ binned) {
    __shared__ u32 pk[CHUNK];
    __shared__ int hist[NBUCK], base[NBUCK], lcur[NBUCK];
    int tid = threadIdx.x;
    int cbase = blockIdx.x * CHUNK;
    if (tid < NBUCK) hist[tid] = 0;
    __syncthreads();
#pragma unroll
    for (int j = 0; j < CHUNK / 256; j++) {
        int k = cbase + j * 256 + tid;
        u32 v = 0xFFFFFFFFu;
        if (k < EP) {
            int src, dst;
            if (k < NE) { src = ei[k]; dst = ei[NE + k]; }
            else        { src = k - NE; dst = src; }
            v = ((u32)dst << 16) | (u32)src;
            atomicAdd(&hist[dst >> 10], 1);
        }
        pk[j * 256 + tid] = v;
    }
    __syncthreads();
    if (tid < NBUCK) {
        base[tid] = atomicAdd(&gcur[tid], hist[tid]);
        lcur[tid] = 0;
    }
    __syncthreads();
#pragma unroll
    for (int j = 0; j < CHUNK / 256; j++) {
        u32 v = pk[j * 256 + tid];
        if (v != 0xFFFFFFFFu) {
            int b = v >> 26;  // (v>>16)>>10
            int pos = base[b] + atomicAdd(&lcur[b], 1);
            binned[(size_t)b * BCAP + pos] = v;
        }
    }
}

// per-(node,chunk) degree count via 16KB LDS histogram (4 blocks per bucket)
__global__ __launch_bounds__(1024) void k_cnt2(const int* __restrict__ gcur,
                                               const u32* __restrict__ binned,
                                               int* __restrict__ deg) {
    __shared__ int hist[4096];   // 1024 nodes x 4 chunks
    int b = blockIdx.x >> 2, sub = blockIdx.x & 3;
#pragma unroll
    for (int j = 0; j < 4; j++) hist[j * 1024 + threadIdx.x] = 0;
    __syncthreads();
    int cnt = gcur[b];
    const u32* bb = binned + (size_t)b * BCAP;
    for (int i = sub * 1024 + threadIdx.x; i < cnt; i += 4096) {
        u32 v = bb[i];
        int idx = (int)((v >> 16) & 1023) * 4 + (int)((v & 0xffffu) >> CSH);
        atomicAdd(&hist[idx], 1);
    }
    __syncthreads();
    int segBase = b << 12;
    for (int i = threadIdx.x; i < 4096; i += 1024) {
        int seg = segBase + i;
        int hv = hist[i];
        if (seg < NSEG && hv) atomicAdd(&deg[seg], hv);
    }
}

#define SCAN_B 1024
__global__ __launch_bounds__(1024) void k_scan1(const int* __restrict__ deg,
                                                int* __restrict__ stmp, int* __restrict__ bsum) {
    __shared__ int sm[SCAN_B];
    int i = blockIdx.x * SCAN_B + threadIdx.x;
    sm[threadIdx.x] = (i < NSEG) ? ((deg[i] + 3) & ~3) : 0;   // 4-aligned segments
    __syncthreads();
    for (int off = 1; off < SCAN_B; off <<= 1) {
        int t = (threadIdx.x >= off) ? sm[threadIdx.x - off] : 0;
        __syncthreads();
        sm[threadIdx.x] += t;
        __syncthreads();
    }
    if (i < NSEG) stmp[i] = sm[threadIdx.x];
    if (threadIdx.x == SCAN_B - 1) bsum[blockIdx.x] = sm[SCAN_B - 1];
}

__global__ void k_scan2(int* __restrict__ bsum, int nb) {
    __shared__ int sm[256];
    int v = (threadIdx.x < nb) ? bsum[threadIdx.x] : 0;
    sm[threadIdx.x] = v;
    __syncthreads();
    for (int off = 1; off < 256; off <<= 1) {
        int t = (threadIdx.x >= off) ? sm[threadIdx.x - off] : 0;
        __syncthreads();
        sm[threadIdx.x] += t;
        __syncthreads();
    }
    if (threadIdx.x < nb) bsum[threadIdx.x] = sm[threadIdx.x];
}

// scan finalize + sentinel pad + cur init (fused k_pad)
__global__ __launch_bounds__(1024) void k_scan3(const int* __restrict__ stmp,
                                                const int* __restrict__ bsum,
                                                const int* __restrict__ deg,
                                                int* __restrict__ rowptr,
                                                int* __restrict__ cur,
                                                u16* __restrict__ csr) {
    int i = blockIdx.x * SCAN_B + threadIdx.x;
    if (i >= NSEG) return;
    int add = (blockIdx.x > 0) ? bsum[blockIdx.x - 1] : 0;
    int end = stmp[i] + add;
    rowptr[i + 1] = end;
    if (i == 0) rowptr[0] = 0;
    int d = deg[i];
    int ad = (d + 3) & ~3;
    int start = end - ad;
    cur[i] = start;
    for (int j = start + d; j < end; ++j) csr[j] = 0xFFFFu;
}

// phase 2: per-bucket scatter into (dst, chunk) segments (4 blocks per bucket)
__global__ __launch_bounds__(1024) void k_scatter(const int* __restrict__ gcur,
                                                  int* __restrict__ cur,
                                                  const u32* __restrict__ binned,
                                                  u16* __restrict__ csr) {
    int b = blockIdx.x >> 2, sub = blockIdx.x & 3;
    int cnt = gcur[b];
    const u32* bb = binned + (size_t)b * BCAP;
    for (int i = sub * 1024 + threadIdx.x; i < cnt; i += 4096) {
        u32 v = bb[i];
        int dst = v >> 16;
        int src = v & 0xffffu;
        int pos = atomicAdd(&cur[dst * NCHUNK + (src >> CSH)], 1);
        csr[pos] = (u16)src;
    }
}

// ------------------------- input projection (fp16 residual carry) ---------------
__global__ void k_in(const float* __restrict__ x, const float* __restrict__ w,
                     const float* __restrict__ b, f16* __restrict__ h16) {
    int t = blockIdx.x * blockDim.x + threadIdx.x;
    if (t >= NN * D) return;
    int n = t >> 7, d = t & 127;
    const float* xr = x + n * 5;
    float acc = b[d];
#pragma unroll
    for (int k = 0; k < 5; k++) acc = fmaf(xr[k], w[k * D + d], acc);
    h16[t] = (f16)acc;
}

// --- MFMA GEMM: xh = h16 @ W16; als/ald via extra MFMA tile (ws); global max ---
__global__ __launch_bounds__(256) void k_gemm(const f16* __restrict__ h16,
                                              const f16* __restrict__ wt,
                                              const f16* __restrict__ ws16,
                                              f16* __restrict__ xh,
                                              float* __restrict__ als,
                                              float* __restrict__ ald,
                                              int* __restrict__ gmaxk) {
    __shared__ int sgk[4];
    if (threadIdx.x < 4) sgk[threadIdx.x] = NEG_INF_KEY;
    int wid = threadIdx.x >> 6;
    int lane = threadIdx.x & 63;
    int wbase = blockIdx.x * 128 + wid * 32;
    int r = lane & 15;
    int g = lane >> 4;

    int arow0 = wbase + r;      if (arow0 >= NN) arow0 = NN - 1;
    int arow1 = wbase + 16 + r; if (arow1 >= NN) arow1 = NN - 1;
    const f16* a0p = h16 + (size_t)arow0 * D + g * 8;
    const f16* a1p = h16 + (size_t)arow1 * D + g * 8;

    f32x4v acc0[8], acc1[8], al0, al1;
#pragma unroll
    for (int nt = 0; nt < 8; nt++) {
        acc0[nt] = (f32x4v){0.f, 0.f, 0.f, 0.f};
        acc1[nt] = (f32x4v){0.f, 0.f, 0.f, 0.f};
    }
    al0 = (f32x4v){0.f, 0.f, 0.f, 0.f};
    al1 = (f32x4v){0.f, 0.f, 0.f, 0.f};

#pragma unroll
    for (int ks = 0; ks < 4; ks++) {
        half8 a0 = *(const half8*)(a0p + ks * 32);
        half8 a1 = *(const half8*)(a1p + ks * 32);
        half8 bal = *(const half8*)(ws16 + (size_t)r * D + ks * 32 + g * 8);
        al0 = __builtin_amdgcn_mfma_f32_16x16x32_f16(a0, bal, al0, 0, 0, 0);
        al1 = __builtin_amdgcn_mfma_f32_16x16x32_f16(a1, bal, al1, 0, 0, 0);
#pragma unroll
        for (int nt = 0; nt < 8; nt++) {
            half8 b = *(const half8*)(wt + (size_t)(nt * 16 + r) * D + ks * 32 + g * 8);
            acc0[nt] = __builtin_amdgcn_mfma_f32_16x16x32_f16(a0, b, acc0[nt], 0, 0, 0);
            acc1[nt] = __builtin_amdgcn_mfma_f32_16x16x32_f16(a1, b, acc1[nt], 0, 0, 0);
        }
    }

#pragma unroll
    for (int rg = 0; rg < 4; rg++) {
        int n0 = wbase + g * 4 + rg;
        if (n0 < NN) {
#pragma unroll
            for (int nt = 0; nt < 8; nt++)
                xh[(size_t)n0 * D + nt * 16 + r] = (f16)acc0[nt][rg];
        }
        int n1 = wbase + 16 + g * 4 + rg;
        if (n1 < NN) {
#pragma unroll
            for (int nt = 0; nt < 8; nt++)
                xh[(size_t)n1 * D + nt * 16 + r] = (f16)acc1[nt][rg];
        }
    }

    float m = -1e30f;
#pragma unroll
    for (int rg = 0; rg < 4; rg++) {
        int n0 = wbase + g * 4 + rg;
        int n1 = wbase + 16 + g * 4 + rg;
        float v0 = al0[rg], v1 = al1[rg];
        if (r < 8) {
            int hh = r >> 1;
            if (r & 1) {
                if (n0 < NN) ald[n0 * H + hh] = v0;
                if (n1 < NN) ald[n1 * H + hh] = v1;
            } else {
                if (n0 < NN) als[n0 * H + hh] = v0;
                if (n1 < NN) als[n1 * H + hh] = v1;
                m = fmaxf(m, fmaxf(v0, v1));
            }
        }
    }
    m = fmaxf(m, __shfl_xor(m, 16));
    m = fmaxf(m, __shfl_xor(m, 32));
    __syncthreads();
    if (lane < 8 && !(r & 1)) atomicMax(&sgk[r >> 1], fkey(m));
    __syncthreads();
    if (threadIdx.x < 4) atomicMax(&gmaxk[threadIdx.x], sgk[threadIdx.x]);
}

// ---- fused aggregation (4 edges/iter, 4 src-chunk passes) + bias + LN + residual
// lane = slot(2b) | q(4b): slot = edge slot 0..3, q -> dims q*8..q*8+7, head = q>>2
__global__ __launch_bounds__(256) void k_agg(const f16* __restrict__ xh,
                                             const float* __restrict__ als,
                                             const float* __restrict__ ald,
                                             const int* __restrict__ gmaxk,
                                             const int* __restrict__ rp,
                                             const u16* __restrict__ csr,
                                             const float* __restrict__ cb,
                                             const float* __restrict__ gamma,
                                             const float* __restrict__ beta,
                                             f16* __restrict__ h16,
                                             float* __restrict__ hout, int do_relu) {
    int node = blockIdx.x * 4 + (threadIdx.x >> 6);
    if (node >= NN) return;
    int lane = threadIdx.x & 63;
    int slot = lane >> 4;
    int q = lane & 15;
    int head = q >> 2;

    int4 rp4 = ((const int4*)rp)[node];
    int e4 = rp[node * 4 + 4];
    int starts[5] = {rp4.x, rp4.y, rp4.z, rp4.w, e4};

    float adH = ald[node * H + head];
    float mH = leakyf(fdec(gmaxk[head]) + adH);   // upper bound on segment max

    float acc[8];
#pragma unroll
    for (int j = 0; j < 8; j++) acc[j] = 0.f;
    float den = 0.f;

    int sh = (slot & 1) << 4;
    bool hiw = (slot & 2) != 0;

#pragma unroll
    for (int p = 0; p < 4; ++p) {
        int s0 = starts[p], s1 = starts[p + 1];
#pragma unroll 2
        for (int e = s0; e < s1; e += 4) {
            uint2 cw = *(const uint2*)(csr + e);          // 4 edge srcs (broadcast)
            unsigned dw = hiw ? cw.y : cw.x;
            unsigned s = (dw >> sh) & 0xffffu;
            bool valid = s != 0xffffu;
            unsigned sc = valid ? s : 0u;
            float al = als[sc * H + head];
            float ev = valid ? __expf(leakyf(al + adH) - mH) : 0.f;
            den += ev;
            half8 pv = *(const half8*)(xh + sc * D + q * 8);
#pragma unroll
            for (int j = 0; j < 8; j++) acc[j] = fmaf(ev, (float)pv[j], acc[j]);
        }
    }

    // reduce edge slots (lanes l, l^16, l^32, l^48 share the same dims)
    den += __shfl_xor(den, 16);
    den += __shfl_xor(den, 32);
#pragma unroll
    for (int j = 0; j < 8; j++) {
        acc[j] += __shfl_xor(acc[j], 16);
        acc[j] += __shfl_xor(acc[j], 32);
    }

    float inv_den = 1.f / (den + 1e-16f);
    float o[8];
    const float4* cb4 = (const float4*)(cb + q * 8);
    float4 cba = cb4[0], cbb = cb4[1];
    o[0] = fmaf(acc[0], inv_den, cba.x);
    o[1] = fmaf(acc[1], inv_den, cba.y);
    o[2] = fmaf(acc[2], inv_den, cba.z);
    o[3] = fmaf(acc[3], inv_den, cba.w);
    o[4] = fmaf(acc[4], inv_den, cbb.x);
    o[5] = fmaf(acc[5], inv_den, cbb.y);
    o[6] = fmaf(acc[6], inv_den, cbb.z);
    o[7] = fmaf(acc[7], inv_den, cbb.w);

    // LayerNorm stats: each lane holds 8 dims; q-lanes 0..15 cover all 128
    float s = 0.f;
#pragma unroll
    for (int j = 0; j < 8; j++) s += o[j];
#pragma unroll
    for (int off = 1; off < 16; off <<= 1) s += __shfl_xor(s, off);
    float mean = s * (1.f / 128.f);
    float v = 0.f;
    float c[8];
#pragma unroll
    for (int j = 0; j < 8; j++) { c[j] = o[j] - mean; v = fmaf(c[j], c[j], v); }
#pragma unroll
    for (int off = 1; off < 16; off <<= 1) v += __shfl_xor(v, off);
    float inv = rsqrtf(v * (1.f / 128.f) + LN_EPS);

    // each lane writes dims q*8 + slot*2 + {0,1}
    int dim = q * 8 + slot * 2;
    float2 g2 = *(const float2*)(gamma + dim);
    float2 b2 = *(const float2*)(beta + dim);
    float r0 = c[slot * 2] * inv * g2.x + b2.x;
    float r1 = c[slot * 2 + 1] * inv * g2.y + b2.y;
    if (do_relu) { r0 = fmaxf(r0, 0.f); r1 = fmaxf(r1, 0.f); }
    half2v hv16 = *(const half2v*)&h16[(size_t)node * D + dim];
    float n0 = (float)hv16[0] + r0;
    float n1 = (float)hv16[1] + r1;
    if (do_relu) {
        half2v h2; h2[0] = (f16)n0; h2[1] = (f16)n1;
        *(half2v*)&h16[(size_t)node * D + dim] = h2;
    } else {
        float2* hp = (float2*)&hout[(size_t)node * D + dim];
        *hp = (float2){n0, n1};
    }
}

// ------------------------- launch -------------------------
extern "C" void kernel_launch(void* const* d_in, const int* in_sizes, int n_in,
                              void* d_out, int out_size, void* d_ws, size_t ws_size,
                              hipStream_t stream) {
    const float* x    = (const float*)d_in[0];
    const float* w_in = (const float*)d_in[1];
    const float* b_in = (const float*)d_in[2];
    const int*   ei   = (const int*)d_in[21];
    float* hout = (float*)d_out;

    char* w = (char*)d_ws;
    int* deg    = (int*)w;  w += (size_t)NSEG * 4;
    int* cur    = (int*)w;  w += (size_t)NSEG * 4;
    int* stmp   = (int*)w;  w += (size_t)NSEG * 4;
    int* bsum   = (int*)w;  w += 1024;
    int* rowptr = (int*)w;  w += (size_t)(NSEG + 8) * 4;
    int* gmaxk  = (int*)w;  w += 64;
    int* gcur   = (int*)w;  w += 256;
    u16* csr    = (u16*)w;  w += (size_t)(EP + 3 * NSEG + 64) * 2;
    f16* h16    = (f16*)w;  w += (size_t)NN * D * 2;
    f16* xh     = (f16*)w;  w += (size_t)NN * D * 2;
    f16* wt     = (f16*)w;  w += (size_t)3 * D * D * 2;
    f16* ws16   = (f16*)w;  w += (size_t)3 * 16 * D * 2;
    float* als  = (float*)w; w += (size_t)NN * H * 4;
    float* ald  = (float*)w; w += (size_t)NN * H * 4;
    u32* binned = (u32*)h16;  // h16 first written by k_in AFTER scatter; 8.03MB < 12.8MB

    k_init<<<(NSEG + 255) / 256, 256, 0, stream>>>(deg, gmaxk, gcur,
                                    (const float*)d_in[3], (const float*)d_in[9],
                                    (const float*)d_in[15], wt,
                                    (const float*)d_in[4], (const float*)d_in[5],
                                    (const float*)d_in[10], (const float*)d_in[11],
                                    (const float*)d_in[16], (const float*)d_in[17],
                                    ws16);
    k_bin<<<(EP + CHUNK - 1) / CHUNK, 256, 0, stream>>>(ei, gcur, binned);
    k_cnt2<<<NBUCK * 4, 1024, 0, stream>>>(gcur, binned, deg);
    int nbScan = (NSEG + SCAN_B - 1) / SCAN_B;  // 196
    k_scan1<<<nbScan, SCAN_B, 0, stream>>>(deg, stmp, bsum);
    k_scan2<<<1, 256, 0, stream>>>(bsum, nbScan);
    k_scan3<<<nbScan, SCAN_B, 0, stream>>>(stmp, bsum, deg, rowptr, cur, csr);
    k_scatter<<<NBUCK * 4, 1024, 0, stream>>>(gcur, cur, binned, csr);

    k_in<<<(NN * D) / 256, 256, 0, stream>>>(x, w_in, b_in, h16);

    for (int L = 0; L < 3; ++L) {
        const float* cb   = (const float*)d_in[6 + 6 * L];
        const float* g    = (const float*)d_in[7 + 6 * L];
        const float* lb   = (const float*)d_in[8 + 6 * L];
        k_gemm<<<(NN + 127) / 128, 256, 0, stream>>>(h16, wt + (size_t)L * D * D,
                                                     ws16 + (size_t)L * 16 * D,
                                                     xh, als, ald, gmaxk + 4 * L);
        k_agg<<<(NN + 3) / 4, 256, 0, stream>>>(xh, als, ald, gmaxk + 4 * L, rowptr, csr,
                                                cb, g, lb, h16, hout, L < 2 ? 1 : 0);
    }
}